// Round 5
// baseline (2591.931 us; speedup 1.0000x reference)
//
#include <hip/hip_runtime.h>
#include <stdint.h>

#define BATCH 512
#define TMAX 1024
#define DIN 4
#define H 64
#define NC 1098
#define CH 192   // layer-1 chunk rows; G1 chunk = CH*512*256*4B = 100.7 MB

__device__ __forceinline__ float sigmoidf_(float x) {
    return 1.0f / (1.0f + __expf(-x));
}
__device__ __forceinline__ float tanhf_(float x) {
    return 1.0f - 2.0f / (__expf(2.0f * x) + 1.0f);
}
// bf16 helpers (RNE) — self-contained, no header dependency
__device__ __forceinline__ uint32_t f2bf(float f) {
    uint32_t u = __float_as_uint(f);
    return (u + 0x7FFFu + ((u >> 16) & 1u)) >> 16;
}
__device__ __forceinline__ float bf2f(uint32_t h) {
    return __uint_as_float(h << 16);
}

// ============ Layer 0: 4-wave gate split, ONE barrier per step ==============
// Wave w owns gate row w*64+j (PyTorch order i,f,g,o -> w=2 is tanh). Each
// wave keeps a PRIVATE h replica in LDS (same-wave ds write->read is in-order,
// no barrier) and redundantly computes the c/h update, so the only cross-wave
// exchange is the 4-gate value via a parity double-buffered LDS buffer ->
// exactly one s_barrier per step. h history ring-buffered by wave0 and flushed
// to global (bf16) every 64 steps so no global store is in flight at the
// per-step barrier (avoids vmcnt(0) drain each step).
__global__ __launch_bounds__(256) void lstm_layer0_w4(
    const float* __restrict__ x, const int* __restrict__ lengths,
    const float* __restrict__ Wih_f, const float* __restrict__ Whh_f,
    const float* __restrict__ bih_f, const float* __restrict__ bhh_f,
    const float* __restrict__ Wih_b, const float* __restrict__ Whh_b,
    const float* __restrict__ bih_b, const float* __restrict__ bhh_b,
    uint16_t* __restrict__ h0b /* [B, T, 2H] bf16 */)
{
    const int unit = blockIdx.x;
    const int b = unit >> 1, dir = unit & 1;
    const int t = threadIdx.x;
    const int j = t & 63, w = t >> 6;
    const int L = lengths[b];

    const float* Wih = dir ? Wih_b : Wih_f;
    const float* Whh = dir ? Whh_b : Whh_f;
    const float* bih = dir ? bih_b : bih_f;
    const float* bhh = dir ? bhh_b : bhh_f;

    const int row = w * H + j;           // this lane's gate row
    float whh[H];
    {
        const float4* wv = (const float4*)(Whh + (size_t)row * H);
        #pragma unroll
        for (int k = 0; k < H / 4; k++) {
            float4 v = wv[k];
            whh[4*k+0]=v.x; whh[4*k+1]=v.y; whh[4*k+2]=v.z; whh[4*k+3]=v.w;
        }
    }
    const float4 wx = ((const float4*)Wih)[row];   // Wih row = 4 floats
    const float bias = bih[row] + bhh[row];

    __shared__ __align__(16) float4 xbuf4[TMAX];   // 16 KB: whole x[b]
    __shared__ __align__(16) float hist[64 * H];   // 16 KB: h ring (wave0)
    __shared__ __align__(16) float hrep[4][H];     // per-wave h replicas
    __shared__ __align__(16) float ex[2][H][4];    // gate exchange, 2-deep

    {
        const float4* x4 = (const float4*)x + (size_t)b * TMAX;
        for (int i = t; i < L; i += 256) xbuf4[i] = x4[i];
    }
    hrep[w][j] = 0.0f;      // own replica: same-wave, no barrier needed
    float c = 0.0f;
    __syncthreads();        // xbuf visibility

    for (int s = 0; s < L; s++) {
        const int tt = dir ? (L - 1 - s) : s;
        const float4 xt = xbuf4[tt];               // broadcast read

        float a0 = bias, a1 = 0.0f, a2 = 0.0f, a3 = 0.0f;
        a0 = fmaf(wx.x, xt.x, a0); a1 = fmaf(wx.y, xt.y, a1);
        a2 = fmaf(wx.z, xt.z, a2); a3 = fmaf(wx.w, xt.w, a3);
        const float4* h4 = (const float4*)hrep[w]; // own replica, in-order
        #pragma unroll
        for (int k = 0; k < H / 4; k++) {
            float4 hv = h4[k];
            a0 = fmaf(whh[4*k+0], hv.x, a0);
            a1 = fmaf(whh[4*k+1], hv.y, a1);
            a2 = fmaf(whh[4*k+2], hv.z, a2);
            a3 = fmaf(whh[4*k+3], hv.w, a3);
        }
        const float a = (a0 + a1) + (a2 + a3);
        const int p = s & 1;
        ex[p][j][w] = (w == 2) ? tanhf_(a) : sigmoidf_(a);
        __syncthreads();                           // the ONLY per-step barrier
        const float4 g4 = *(const float4*)ex[p][j]; // i,f,g,o
        c = fmaf(g4.y, c, g4.x * g4.z);
        const float h = g4.w * tanhf_(c);
        hrep[w][j] = h;                            // own replica
        if (w == 0) {
            hist[(s & 63) * H + j] = h;
            if ((s & 63) == 63 || s == L - 1) {
                // wave0 flushes its own writes (in-order, no barrier needed)
                const int s0c = s & ~63, nrows = s - s0c + 1;
                const int q = j & 3;
                for (int rr = j >> 2; rr < nrows; rr += 16) {
                    const int t2 = dir ? (L - 1 - (s0c + rr)) : (s0c + rr);
                    const float* src = hist + rr * H + q * 16;
                    uint16_t* dst = h0b + ((size_t)b * TMAX + t2) * (2*H) + dir * H + q * 16;
                    uint32_t pk[8];
                    #pragma unroll
                    for (int q2 = 0; q2 < 8; q2++)
                        pk[q2] = f2bf(src[2*q2]) | (f2bf(src[2*q2+1]) << 16);
                    ((uint4*)dst)[0] = make_uint4(pk[0], pk[1], pk[2], pk[3]);
                    ((uint4*)dst)[1] = make_uint4(pk[4], pk[5], pk[6], pk[7]);
                }
            }
        }
    }
}

// ============ Layer 1 xW GEMM (chunk): G1c = h0[:,s0:s0+CH] @ Wih^T + b =====
// h0 is bf16; staged->fp32 LDS; weights fp32 in regs. Output row layout
// [r][g] with g = gate*64+j -> coalesced writes, conflict-free rec reads.
__global__ __launch_bounds__(256) void xw_gemm_chunk(
    const uint16_t* __restrict__ h0b, const int* __restrict__ lengths,
    const float* __restrict__ Wih, const float* __restrict__ bih,
    const float* __restrict__ bhh, float* __restrict__ G1c, int s0)
{
    const int b  = blockIdx.y;
    const int r0 = s0 + blockIdx.x * 64;
    const int L  = lengths[b];
    if (r0 >= L) return;
    const int V = min(64, L - r0);
    const int g = threadIdx.x;

    float wreg[2*H];
    {
        const float4* wv = (const float4*)(Wih + (size_t)g * (2*H));
        #pragma unroll
        for (int k = 0; k < (2*H) / 4; k++) {
            float4 v = wv[k];
            wreg[4*k+0]=v.x; wreg[4*k+1]=v.y; wreg[4*k+2]=v.z; wreg[4*k+3]=v.w;
        }
    }
    const float bb = bih[g] + bhh[g];

    __shared__ __align__(16) float xs[64 * 128];   // 32 KB fp32
    {
        const uint4* src = (const uint4*)(h0b + ((size_t)b * TMAX + r0) * (2*H));
        for (int i = g; i < V * 16; i += 256) {    // 16 uint4 per row
            uint4 u = src[i];
            float* d = xs + i * 8;
            d[0] = bf2f(u.x & 0xFFFFu); d[1] = bf2f(u.x >> 16);
            d[2] = bf2f(u.y & 0xFFFFu); d[3] = bf2f(u.y >> 16);
            d[4] = bf2f(u.z & 0xFFFFu); d[5] = bf2f(u.z >> 16);
            d[6] = bf2f(u.w & 0xFFFFu); d[7] = bf2f(u.w >> 16);
        }
    }
    __syncthreads();

    for (int r = 0; r < V; r++) {
        const float4* xr = (const float4*)(xs + r * 128);
        float a0 = bb, a1 = 0.0f, a2 = 0.0f, a3 = 0.0f;
        #pragma unroll
        for (int k = 0; k < 32; k++) {
            float4 v = xr[k];
            a0 = fmaf(wreg[4*k+0], v.x, a0);
            a1 = fmaf(wreg[4*k+1], v.y, a1);
            a2 = fmaf(wreg[4*k+2], v.z, a2);
            a3 = fmaf(wreg[4*k+3], v.w, a3);
        }
        G1c[((size_t)b * CH + (r0 - s0 + r)) * 256 + g] = (a0 + a1) + (a2 + a3);
    }
}

// ============ Layer 1 recurrence chunk: 4-wave split, ONE barrier/step ======
// Same sync structure as layer0 (private h replicas + parity exchange). Only
// the K=64 Whh dot is serial; G1 rows bulk-staged into LDS every 64 steps.
// c replicated per wave (each wave updates redundantly). Epilogue (bwd first
// step, zero state -> Whh_l1b unused + logits) fused into the final chunk.
__global__ __launch_bounds__(256) void lstm_rec_w4(
    const float* __restrict__ G1c, const uint16_t* __restrict__ h0b,
    const int* __restrict__ lengths, const float* __restrict__ Whh,
    const float* __restrict__ Wih_b,
    const float* __restrict__ bih_b, const float* __restrict__ bhh_b,
    const float* __restrict__ Wout, const float* __restrict__ bout,
    float* __restrict__ out, float* __restrict__ state, int s0)
{
    const int b = blockIdx.x;
    const int t = threadIdx.x;
    const int j = t & 63, w = t >> 6;
    const int L = lengths[b];
    if (L <= s0) return;
    const int send = min(L, s0 + CH);

    const int row = w * H + j;
    float whh[H];
    {
        const float4* wv = (const float4*)(Whh + (size_t)row * H);
        #pragma unroll
        for (int k = 0; k < H / 4; k++) {
            float4 v = wv[k];
            whh[4*k+0]=v.x; whh[4*k+1]=v.y; whh[4*k+2]=v.z; whh[4*k+3]=v.w;
        }
    }

    __shared__ __align__(16) float gbuf[64 * 256]; // 64 KB: 64 G1 rows
    __shared__ __align__(16) float hrep[4][H];
    __shared__ __align__(16) float ex[2][H][4];

    float c, h = 0.0f;
    if (s0 == 0) {
        c = 0.0f;
        hrep[w][j] = 0.0f;
    } else {
        c = state[(size_t)b * 128 + j];
        h = state[(size_t)b * 128 + 64 + j];
        hrep[w][j] = h;
    }

    for (int s = s0; s < send; s++) {
        const int r = s - s0;
        if ((r & 63) == 0) {
            const int nr = min(64, send - s);
            const float4* srcv = (const float4*)(G1c + ((size_t)b * CH + r) * 256);
            float4* dstv = (float4*)gbuf;
            for (int i = t; i < nr * 64; i += 256) dstv[i] = srcv[i];
            __syncthreads();                       // one drain per 64 steps
        }
        const int rr = r & 63;
        float a0 = gbuf[rr * 256 + row], a1 = 0.0f, a2 = 0.0f, a3 = 0.0f;
        const float4* h4 = (const float4*)hrep[w];
        #pragma unroll
        for (int k = 0; k < H / 4; k++) {
            float4 hv = h4[k];
            a0 = fmaf(whh[4*k+0], hv.x, a0);
            a1 = fmaf(whh[4*k+1], hv.y, a1);
            a2 = fmaf(whh[4*k+2], hv.z, a2);
            a3 = fmaf(whh[4*k+3], hv.w, a3);
        }
        const float a = (a0 + a1) + (a2 + a3);
        const int p = s & 1;
        ex[p][j][w] = (w == 2) ? tanhf_(a) : sigmoidf_(a);
        __syncthreads();
        const float4 g4 = *(const float4*)ex[p][j];
        c = fmaf(g4.y, c, g4.x * g4.z);
        h = g4.w * tanhf_(c);
        hrep[w][j] = h;
    }

    if (send < L) {
        if (w == 0) {
            state[(size_t)b * 128 + j]      = c;
            state[(size_t)b * 128 + 64 + j] = h;
        }
        return;
    }

    // ---- epilogue: y = [h1f_last, h1b_first]; logits = y @ Wout^T + bout ---
    __shared__ __align__(16) float ybuf[2*H];
    __shared__ __align__(16) float xsb[2*H];
    if (w == 0) ybuf[j] = h;
    if (t < 2*H)
        xsb[t] = bf2f(h0b[((size_t)b * TMAX + (L - 1)) * (2*H) + t]);
    __syncthreads();

    {   // bwd first step, zero state: wave w computes its gate row
        float e0 = bih_b[row] + bhh_b[row], e1 = 0.0f, e2 = 0.0f, e3 = 0.0f;
        const float4* wr = (const float4*)(Wih_b + (size_t)row * (2*H));
        const float4* xv = (const float4*)xsb;
        #pragma unroll
        for (int k = 0; k < (2*H) / 4; k++) {
            float4 wv = wr[k], xk = xv[k];
            e0 = fmaf(wv.x, xk.x, e0);
            e1 = fmaf(wv.y, xk.y, e1);
            e2 = fmaf(wv.z, xk.z, e2);
            e3 = fmaf(wv.w, xk.w, e3);
        }
        const float aa = (e0 + e1) + (e2 + e3);
        ex[0][j][w] = (w == 2) ? tanhf_(aa) : sigmoidf_(aa);
    }
    __syncthreads();
    if (w == 0) {
        const float4 g4 = *(const float4*)ex[0][j];
        const float cb = g4.x * g4.z;              // c_prev = 0, f unused
        ybuf[H + j] = g4.w * tanhf_(cb);
    }
    __syncthreads();

    const float4* yv = (const float4*)ybuf;
    for (int o = t; o < NC; o += 256) {
        float a0 = bout[o], a1 = 0.0f, a2 = 0.0f, a3 = 0.0f;
        const float4* wr = (const float4*)(Wout + (size_t)o * (2*H));
        #pragma unroll
        for (int k = 0; k < (2*H) / 4; k++) {
            float4 w2 = wr[k]; float4 yy = yv[k];
            a0 = fmaf(w2.x, yy.x, a0);
            a1 = fmaf(w2.y, yy.y, a1);
            a2 = fmaf(w2.z, yy.z, a2);
            a3 = fmaf(w2.w, yy.w, a3);
        }
        out[(size_t)b * NC + o] = (a0 + a1) + (a2 + a3);
    }
}

extern "C" void kernel_launch(void* const* d_in, const int* in_sizes, int n_in,
                              void* d_out, int out_size, void* d_ws, size_t ws_size,
                              hipStream_t stream) {
    const float* x        = (const float*)d_in[0];
    const int*   lengths  = (const int*)  d_in[1];
    const float* Wih_l0f  = (const float*)d_in[2];
    const float* Whh_l0f  = (const float*)d_in[3];
    const float* bih_l0f  = (const float*)d_in[4];
    const float* bhh_l0f  = (const float*)d_in[5];
    const float* Wih_l0b  = (const float*)d_in[6];
    const float* Whh_l0b  = (const float*)d_in[7];
    const float* bih_l0b  = (const float*)d_in[8];
    const float* bhh_l0b  = (const float*)d_in[9];
    const float* Wih_l1f  = (const float*)d_in[10];
    const float* Whh_l1f  = (const float*)d_in[11];
    const float* bih_l1f  = (const float*)d_in[12];
    const float* bhh_l1f  = (const float*)d_in[13];
    const float* Wih_l1b  = (const float*)d_in[14];
    // d_in[15] = Whh_l1b: unused (backward dir only needs its first step, h=0)
    const float* bih_l1b  = (const float*)d_in[16];
    const float* bhh_l1b  = (const float*)d_in[17];
    const float* Wout     = (const float*)d_in[18];
    const float* bout     = (const float*)d_in[19];
    float* out = (float*)d_out;

    // ws budget (ws_size proven >= 256 MiB by R1-R4 passing with 256 MiB h0):
    //   h0 bf16  [B,T,2H] = 128 MiB
    //   state fp32 [B,128] = 256 KiB
    //   G1 fp32 chunk [B,CH,256] = 100.7 MiB        total ~229 MiB
    const size_t h0_bytes = (size_t)BATCH * TMAX * (2*H) * sizeof(uint16_t);
    const size_t st_bytes = (size_t)BATCH * 2 * H * sizeof(float);
    uint16_t* h0b  = (uint16_t*)d_ws;
    float*    state = (float*)((char*)d_ws + h0_bytes);
    float*    G1c   = (float*)((char*)d_ws + h0_bytes + st_bytes);

    lstm_layer0_w4<<<dim3(2 * BATCH), 256, 0, stream>>>(
        x, lengths,
        Wih_l0f, Whh_l0f, bih_l0f, bhh_l0f,
        Wih_l0b, Whh_l0b, bih_l0b, bhh_l0b, h0b);

    for (int s0 = 0; s0 < TMAX; s0 += CH) {
        xw_gemm_chunk<<<dim3(CH / 64, BATCH), 256, 0, stream>>>(
            h0b, lengths, Wih_l1f, bih_l1f, bhh_l1f, G1c, s0);
        lstm_rec_w4<<<dim3(BATCH), 256, 0, stream>>>(
            G1c, h0b, lengths, Whh_l1f,
            Wih_l1b, bih_l1b, bhh_l1b, Wout, bout, out, state, s0);
    }
}

// Round 6
// 1845.052 us; speedup vs baseline: 1.4048x; 1.4048x over previous
//
#include <hip/hip_runtime.h>
#include <stdint.h>

#define BATCH 512
#define TMAX 1024
#define DIN 4
#define H 64
#define NC 1098
#define RCH 32   // rec kernel: h0 rows staged in LDS per chunk

__device__ __forceinline__ float sigmoidf_(float x) {
    return 1.0f / (1.0f + __expf(-x));
}
__device__ __forceinline__ float tanhf_(float x) {
    return 1.0f - 2.0f / (__expf(2.0f * x) + 1.0f);
}
// bf16 helpers (RNE)
__device__ __forceinline__ uint32_t f2bf(float f) {
    uint32_t u = __float_as_uint(f);
    return (u + 0x7FFFu + ((u >> 16) & 1u)) >> 16;
}
__device__ __forceinline__ float bf2f(uint32_t h) {
    return __uint_as_float(h << 16);
}

// ============ Layer 0: 4-wave gate split, ONE barrier per step ==============
// Wave w owns gate row w*64+j (i,f,g,o -> w=2 is tanh). Private per-wave h
// replicas (same-wave ds write->read is in-order, no barrier); redundant c/h
// update per wave; parity double-buffered gate exchange -> 1 barrier/step.
// Exchange layout [p][w][j]: stride-1 writes, 4x stride-1 b32 reads
// (conflict-free; R5's [p][j][w] was 8/16-way conflicted, 1.38e7 cycles).
// h ring flushed to bf16 global every 64 steps (keeps stores out of the
// per-step barrier window), float2/row-pair pattern = 2 lanes/bank (free).
__global__ __launch_bounds__(256, 4) void lstm_layer0_w4(
    const float* __restrict__ x, const int* __restrict__ lengths,
    const float* __restrict__ Wih_f, const float* __restrict__ Whh_f,
    const float* __restrict__ bih_f, const float* __restrict__ bhh_f,
    const float* __restrict__ Wih_b, const float* __restrict__ Whh_b,
    const float* __restrict__ bih_b, const float* __restrict__ bhh_b,
    uint16_t* __restrict__ h0b /* [B, T, 2H] bf16 */)
{
    const int unit = blockIdx.x;
    const int b = unit >> 1, dir = unit & 1;
    const int t = threadIdx.x;
    const int j = t & 63, w = t >> 6;
    const int L = lengths[b];

    const float* Wih = dir ? Wih_b : Wih_f;
    const float* Whh = dir ? Whh_b : Whh_f;
    const float* bih = dir ? bih_b : bih_f;
    const float* bhh = dir ? bhh_b : bhh_f;

    const int row = w * H + j;
    float whh[H];
    {
        const float4* wv = (const float4*)(Whh + (size_t)row * H);
        #pragma unroll
        for (int k = 0; k < H / 4; k++) {
            float4 v = wv[k];
            whh[4*k+0]=v.x; whh[4*k+1]=v.y; whh[4*k+2]=v.z; whh[4*k+3]=v.w;
        }
    }
    const float4 wx = ((const float4*)Wih)[row];
    const float bias = bih[row] + bhh[row];

    __shared__ __align__(16) float4 xbuf4[TMAX];   // 16 KB: whole x[b]
    __shared__ __align__(16) float hist[64 * H];   // 16 KB: h ring (wave0)
    __shared__ __align__(16) float hrep[4][H];     // per-wave h replicas
    __shared__ __align__(16) float ex[2][4][H];    // gate exchange, parity

    {
        const float4* x4 = (const float4*)x + (size_t)b * TMAX;
        for (int i = t; i < L; i += 256) xbuf4[i] = x4[i];
    }
    hrep[w][j] = 0.0f;
    float c = 0.0f;
    __syncthreads();

    for (int s = 0; s < L; s++) {
        const int tt = dir ? (L - 1 - s) : s;
        const float4 xt = xbuf4[tt];               // uniform -> broadcast

        float a0 = bias, a1 = 0.0f, a2 = 0.0f, a3 = 0.0f;
        a0 = fmaf(wx.x, xt.x, a0); a1 = fmaf(wx.y, xt.y, a1);
        a2 = fmaf(wx.z, xt.z, a2); a3 = fmaf(wx.w, xt.w, a3);
        const float4* h4 = (const float4*)hrep[w]; // own replica, in-order
        #pragma unroll
        for (int k = 0; k < H / 4; k++) {
            float4 hv = h4[k];
            a0 = fmaf(whh[4*k+0], hv.x, a0);
            a1 = fmaf(whh[4*k+1], hv.y, a1);
            a2 = fmaf(whh[4*k+2], hv.z, a2);
            a3 = fmaf(whh[4*k+3], hv.w, a3);
        }
        const float a = (a0 + a1) + (a2 + a3);
        const int p = s & 1;
        ex[p][w][j] = (w == 2) ? tanhf_(a) : sigmoidf_(a);
        __syncthreads();                           // the ONLY per-step barrier
        const float gi = ex[p][0][j], gf = ex[p][1][j];
        const float gg = ex[p][2][j], go = ex[p][3][j];
        c = fmaf(gf, c, gi * gg);
        const float h = go * tanhf_(c);
        hrep[w][j] = h;
        if (w == 0) {
            hist[(s & 63) * H + j] = h;
            if ((s & 63) == 63 || s == L - 1) {
                const int s0c = s & ~63, nrows = s - s0c + 1;
                const int jc = j & 31, jr = j >> 5;  // 2 rows per iteration
                for (int base = 0; base + jr < nrows; base += 2) {
                    const int rr = base + jr;
                    const int t2 = dir ? (L - 1 - (s0c + rr)) : (s0c + rr);
                    const float2 hv = *(const float2*)(hist + rr * H + jc * 2);
                    const uint32_t pk = f2bf(hv.x) | (f2bf(hv.y) << 16);
                    *(uint32_t*)(h0b + ((size_t)b * TMAX + t2) * (2*H) + dir * H + jc * 2) = pk;
                }
            }
        }
    }
}

// ===== Layer 1: fused xW + recurrence, 4-wave gate split, 1 barrier/step ====
// The xW dot (128 FMA/lane, no serial dependency) runs inline each step,
// filling the latency shadow of the serial Whh dot + barrier — this replaces
// R5's separate GEMM (which ran at 4.5% occupancy) and its 12 extra launches.
// h0 rows staged bf16->fp32 into LDS every RCH steps; per-step reads are
// uniform b128 broadcasts. Epilogue (bwd first step, zero state -> Whh_l1b
// unused, + logits) fused at the end. Single launch for all 1024 steps.
__global__ __launch_bounds__(256, 2) void lstm_rec_fused(
    const uint16_t* __restrict__ h0b, const int* __restrict__ lengths,
    const float* __restrict__ Wih_f, const float* __restrict__ Whh_f,
    const float* __restrict__ bih_f, const float* __restrict__ bhh_f,
    const float* __restrict__ Wih_b,
    const float* __restrict__ bih_b, const float* __restrict__ bhh_b,
    const float* __restrict__ Wout, const float* __restrict__ bout,
    float* __restrict__ out)
{
    const int b = blockIdx.x;
    const int t = threadIdx.x;
    const int j = t & 63, w = t >> 6;
    const int L = lengths[b];

    const int row = w * H + j;
    float wih[2*H];
    {
        const float4* wv = (const float4*)(Wih_f + (size_t)row * (2*H));
        #pragma unroll
        for (int k = 0; k < (2*H) / 4; k++) {
            float4 v = wv[k];
            wih[4*k+0]=v.x; wih[4*k+1]=v.y; wih[4*k+2]=v.z; wih[4*k+3]=v.w;
        }
    }
    float whh[H];
    {
        const float4* wv = (const float4*)(Whh_f + (size_t)row * H);
        #pragma unroll
        for (int k = 0; k < H / 4; k++) {
            float4 v = wv[k];
            whh[4*k+0]=v.x; whh[4*k+1]=v.y; whh[4*k+2]=v.z; whh[4*k+3]=v.w;
        }
    }
    const float bias = bih_f[row] + bhh_f[row];

    __shared__ __align__(16) float xch[RCH * 128]; // 16 KB: staged h0 rows
    __shared__ __align__(16) float hrep[4][H];
    __shared__ __align__(16) float ex[2][4][H];
    __shared__ __align__(16) float ybuf[2*H];

    hrep[w][j] = 0.0f;
    float c = 0.0f, h = 0.0f;

    for (int s = 0; s < L; s++) {
        const int rr = s & (RCH - 1);
        if (rr == 0) {
            __syncthreads();   // protect xch from stragglers of prior chunk
            const int nr = min(RCH, L - s);
            const uint4* src = (const uint4*)(h0b + ((size_t)b * TMAX + s) * (2*H));
            for (int i = t; i < nr * 16; i += 256) {
                uint4 u = src[i];
                float* d = xch + i * 8;
                d[0] = bf2f(u.x & 0xFFFFu); d[1] = bf2f(u.x >> 16);
                d[2] = bf2f(u.y & 0xFFFFu); d[3] = bf2f(u.y >> 16);
                d[4] = bf2f(u.z & 0xFFFFu); d[5] = bf2f(u.z >> 16);
                d[6] = bf2f(u.w & 0xFFFFu); d[7] = bf2f(u.w >> 16);
            }
            __syncthreads();
        }
        // xW: 32 uniform b128 broadcasts + 128 independent FMA (fills the
        // latency shadow of the serial part)
        float a0 = bias, a1 = 0.0f, a2 = 0.0f, a3 = 0.0f;
        const float4* xr = (const float4*)(xch + rr * 128);
        #pragma unroll
        for (int k = 0; k < 32; k++) {
            float4 v = xr[k];
            a0 = fmaf(wih[4*k+0], v.x, a0);
            a1 = fmaf(wih[4*k+1], v.y, a1);
            a2 = fmaf(wih[4*k+2], v.z, a2);
            a3 = fmaf(wih[4*k+3], v.w, a3);
        }
        // Whh dot on own h replica (serial-dependent)
        const float4* h4 = (const float4*)hrep[w];
        #pragma unroll
        for (int k = 0; k < H / 4; k++) {
            float4 hv = h4[k];
            a0 = fmaf(whh[4*k+0], hv.x, a0);
            a1 = fmaf(whh[4*k+1], hv.y, a1);
            a2 = fmaf(whh[4*k+2], hv.z, a2);
            a3 = fmaf(whh[4*k+3], hv.w, a3);
        }
        const float a = (a0 + a1) + (a2 + a3);
        const int p = s & 1;
        ex[p][w][j] = (w == 2) ? tanhf_(a) : sigmoidf_(a);
        __syncthreads();
        const float gi = ex[p][0][j], gf = ex[p][1][j];
        const float gg = ex[p][2][j], go = ex[p][3][j];
        c = fmaf(gf, c, gi * gg);
        h = go * tanhf_(c);
        hrep[w][j] = h;
    }

    // ---- epilogue: y = [h1f_last, h1b_first]; logits = y @ Wout^T + bout ---
    // h0 row L-1 is still resident in xch (row (L-1) & (RCH-1)), fp32.
    const float* xsb = xch + ((L - 1) & (RCH - 1)) * 128;
    if (w == 0) ybuf[j] = h;

    {   // bwd first step, zero state: wave w computes its gate row
        float e0 = bih_b[row] + bhh_b[row], e1 = 0.0f, e2 = 0.0f, e3 = 0.0f;
        const float4* wr = (const float4*)(Wih_b + (size_t)row * (2*H));
        const float4* xv = (const float4*)xsb;
        #pragma unroll
        for (int k = 0; k < (2*H) / 4; k++) {
            float4 wv = wr[k], xk = xv[k];
            e0 = fmaf(wv.x, xk.x, e0);
            e1 = fmaf(wv.y, xk.y, e1);
            e2 = fmaf(wv.z, xk.z, e2);
            e3 = fmaf(wv.w, xk.w, e3);
        }
        const float aa = (e0 + e1) + (e2 + e3);
        ex[0][w][j] = (w == 2) ? tanhf_(aa) : sigmoidf_(aa);
    }
    __syncthreads();
    if (w == 0) {
        const float gi = ex[0][0][j], gg = ex[0][2][j], go = ex[0][3][j];
        const float cb = gi * gg;                  // c_prev = 0, f unused
        ybuf[H + j] = go * tanhf_(cb);
    }
    __syncthreads();

    const float4* yv = (const float4*)ybuf;
    for (int o = t; o < NC; o += 256) {
        float a0 = bout[o], a1 = 0.0f, a2 = 0.0f, a3 = 0.0f;
        const float4* wr = (const float4*)(Wout + (size_t)o * (2*H));
        #pragma unroll
        for (int k = 0; k < (2*H) / 4; k++) {
            float4 w2 = wr[k]; float4 yy = yv[k];
            a0 = fmaf(w2.x, yy.x, a0);
            a1 = fmaf(w2.y, yy.y, a1);
            a2 = fmaf(w2.z, yy.z, a2);
            a3 = fmaf(w2.w, yy.w, a3);
        }
        out[(size_t)b * NC + o] = (a0 + a1) + (a2 + a3);
    }
}

extern "C" void kernel_launch(void* const* d_in, const int* in_sizes, int n_in,
                              void* d_out, int out_size, void* d_ws, size_t ws_size,
                              hipStream_t stream) {
    const float* x        = (const float*)d_in[0];
    const int*   lengths  = (const int*)  d_in[1];
    const float* Wih_l0f  = (const float*)d_in[2];
    const float* Whh_l0f  = (const float*)d_in[3];
    const float* bih_l0f  = (const float*)d_in[4];
    const float* bhh_l0f  = (const float*)d_in[5];
    const float* Wih_l0b  = (const float*)d_in[6];
    const float* Whh_l0b  = (const float*)d_in[7];
    const float* bih_l0b  = (const float*)d_in[8];
    const float* bhh_l0b  = (const float*)d_in[9];
    const float* Wih_l1f  = (const float*)d_in[10];
    const float* Whh_l1f  = (const float*)d_in[11];
    const float* bih_l1f  = (const float*)d_in[12];
    const float* bhh_l1f  = (const float*)d_in[13];
    const float* Wih_l1b  = (const float*)d_in[14];
    // d_in[15] = Whh_l1b: unused (backward dir only needs its first step, h=0)
    const float* bih_l1b  = (const float*)d_in[16];
    const float* bhh_l1b  = (const float*)d_in[17];
    const float* Wout     = (const float*)d_in[18];
    const float* bout     = (const float*)d_in[19];
    float* out = (float*)d_out;

    // ws: h0 bf16 [B,T,2H] = 128 MiB only (ws proven >= 256 MiB)
    uint16_t* h0b = (uint16_t*)d_ws;

    lstm_layer0_w4<<<dim3(2 * BATCH), 256, 0, stream>>>(
        x, lengths,
        Wih_l0f, Whh_l0f, bih_l0f, bhh_l0f,
        Wih_l0b, Whh_l0b, bih_l0b, bhh_l0b, h0b);

    lstm_rec_fused<<<dim3(BATCH), 256, 0, stream>>>(
        h0b, lengths,
        Wih_l1f, Whh_l1f, bih_l1f, bhh_l1f,
        Wih_l1b, bih_l1b, bhh_l1b, Wout, bout, out);
}

// Round 7
// 1437.214 us; speedup vs baseline: 1.8034x; 1.2838x over previous
//
#include <hip/hip_runtime.h>
#include <stdint.h>

#define BATCH 512
#define TMAX 1024
#define DIN 4
#define H 64
#define NC 1098
#define RCH 32   // rec kernel: h0 rows staged in LDS per chunk (power of 2)

typedef __attribute__((ext_vector_type(2))) float v2;

__device__ __forceinline__ v2 mkv2(float a, float b) { v2 r; r.x = a; r.y = b; return r; }

__device__ __forceinline__ float sigmoidf_(float x) {
    return 1.0f / (1.0f + __expf(-x));
}
__device__ __forceinline__ float tanhf_(float x) {
    return 1.0f - 2.0f / (__expf(2.0f * x) + 1.0f);
}
// bf16 helpers (RNE)
__device__ __forceinline__ uint32_t f2bf(float f) {
    uint32_t u = __float_as_uint(f);
    return (u + 0x7FFFu + ((u >> 16) & 1u)) >> 16;
}
__device__ __forceinline__ float bf2f(uint32_t h) {
    return __uint_as_float(h << 16);
}

// ============ Layer 0: 2-wave gate split, ONE barrier per step ==============
// Wave 0 owns gates {i,f} of h-index j=lane, wave 1 owns {g,o}. 136 weight
// floats/lane, BARE __launch_bounds__(128): the (N,minwaves) form made the
// allocator spill weight arrays wholesale to scratch in R3-R6 (VGPR 56-124
// with 64-192-float arrays) -- the per-step scratch reloads were the real
// ~1400cyc/step stall. float2 ext-vector math -> v_pk_fma_f32 halves issue.
// Private per-wave h replicas (same-wave ds write->read in-order, no barrier);
// both waves update c,h redundantly; parity-buffered b64 gate exchange.
__global__ __launch_bounds__(128) void lstm_layer0_p2(
    const float* __restrict__ x, const int* __restrict__ lengths,
    const float* __restrict__ Wih_f, const float* __restrict__ Whh_f,
    const float* __restrict__ bih_f, const float* __restrict__ bhh_f,
    const float* __restrict__ Wih_b, const float* __restrict__ Whh_b,
    const float* __restrict__ bih_b, const float* __restrict__ bhh_b,
    uint16_t* __restrict__ h0b /* [B, T, 2H] bf16 */)
{
    const int unit = blockIdx.x;
    const int b = unit >> 1, dir = unit & 1;
    const int t = threadIdx.x;
    const int j = t & 63, w = t >> 6;   // w in {0,1}
    const int L = lengths[b];

    const float* Wih = dir ? Wih_b : Wih_f;
    const float* Whh = dir ? Whh_b : Whh_f;
    const float* bih = dir ? bih_b : bih_f;
    const float* bhh = dir ? bhh_b : bhh_f;

    const int rA = (2*w) * H + j;       // wave0: i ; wave1: g
    const int rB = (2*w + 1) * H + j;   // wave0: f ; wave1: o

    v2 wA[32], wB[32];
    {
        const float4* pa = (const float4*)(Whh + (size_t)rA * H);
        const float4* pb = (const float4*)(Whh + (size_t)rB * H);
        #pragma unroll
        for (int k = 0; k < 16; k++) {
            float4 va = pa[k], vb = pb[k];
            wA[2*k] = mkv2(va.x, va.y); wA[2*k+1] = mkv2(va.z, va.w);
            wB[2*k] = mkv2(vb.x, vb.y); wB[2*k+1] = mkv2(vb.z, vb.w);
        }
    }
    const float4 wxA = ((const float4*)Wih)[rA];
    const float4 wxB = ((const float4*)Wih)[rB];
    const float bA = bih[rA] + bhh[rA];
    const float bB = bih[rB] + bhh[rB];

    __shared__ __align__(16) float4 xbuf4[TMAX];  // 16 KB: whole x[b]
    __shared__ __align__(16) float hist[32 * H];  // 8 KB: h ring (wave0)
    __shared__ __align__(16) float hrep[2][H];    // per-wave h replicas
    __shared__ __align__(16) v2 ex2[2][2][H];     // parity gate exchange (b64)

    {
        const float4* x4 = (const float4*)x + (size_t)b * TMAX;
        for (int i = t; i < L; i += 128) xbuf4[i] = x4[i];
    }
    hrep[w][j] = 0.0f;
    float c = 0.0f;
    __syncthreads();

    for (int s = 0; s < L; s++) {
        const int tt = dir ? (L - 1 - s) : s;
        const float4 xt = xbuf4[tt];              // uniform -> broadcast

        v2 aA0 = mkv2(bA, 0.0f), aA1 = mkv2(0.0f, 0.0f);
        v2 aB0 = mkv2(bB, 0.0f), aB1 = mkv2(0.0f, 0.0f);
        {
            v2 xlo = mkv2(xt.x, xt.y), xhi = mkv2(xt.z, xt.w);
            aA0 += mkv2(wxA.x, wxA.y) * xlo; aA1 += mkv2(wxA.z, wxA.w) * xhi;
            aB0 += mkv2(wxB.x, wxB.y) * xlo; aB1 += mkv2(wxB.z, wxB.w) * xhi;
        }
        const float4* h4 = (const float4*)hrep[w];
        #pragma unroll
        for (int k = 0; k < 16; k++) {
            float4 hv = h4[k];
            v2 hlo = mkv2(hv.x, hv.y), hhi = mkv2(hv.z, hv.w);
            aA0 += wA[2*k] * hlo; aA1 += wA[2*k+1] * hhi;
            aB0 += wB[2*k] * hlo; aB1 += wB[2*k+1] * hhi;
        }
        const float aAs = (aA0.x + aA0.y) + (aA1.x + aA1.y);
        const float aBs = (aB0.x + aB0.y) + (aB1.x + aB1.y);
        // wave0: i,f both sigmoid; wave1: g tanh, o sigmoid (wave-uniform)
        const float actA = (w == 1) ? tanhf_(aAs) : sigmoidf_(aAs);
        const float actB = sigmoidf_(aBs);
        const int p = s & 1;
        ex2[p][w][j] = mkv2(actA, actB);          // b64, 2 lanes/bank (free)
        __syncthreads();                          // the ONLY per-step barrier
        const v2 other = ex2[p][1 - w][j];
        const float gi = w ? other.x : actA;
        const float gf = w ? other.y : actB;
        const float gg = w ? actA : other.x;
        const float go = w ? actB : other.y;
        c = fmaf(gf, c, gi * gg);
        const float h = go * tanhf_(c);
        hrep[w][j] = h;
        if (w == 0) {
            hist[(s & 31) * H + j] = h;
            if ((s & 31) == 31 || s == L - 1) {   // flush (0 conflicts in R6)
                const int s0c = s & ~31, nrows = s - s0c + 1;
                const int jc = j & 31, jr = j >> 5;
                for (int base = 0; base + jr < nrows; base += 2) {
                    const int rr = base + jr;
                    const int t2 = dir ? (L - 1 - (s0c + rr)) : (s0c + rr);
                    const float2 hv = *(const float2*)(hist + rr * H + jc * 2);
                    const uint32_t pk = f2bf(hv.x) | (f2bf(hv.y) << 16);
                    *(uint32_t*)(h0b + ((size_t)b * TMAX + t2) * (2*H) + dir * H + jc * 2) = pk;
                }
            }
        }
    }
}

// ====== Layer 1: producer/consumer wave pipeline, ONE barrier per step ======
// 512 threads, one sequence per block. Waves 0-3 (producers) compute the xW
// partials for step s+1 (wave w owns k-slice [32w,32w+32), lane j owns gates
// 4j..4j+3 -> 128 weight floats; 8 b128 broadcast reads + 1 b128 write).
// Waves 4-7 (consumers) own gate row (w-4)*64+j: gather 4 partials + bias,
// serial Whh dot on a private h replica, activation, parity exchange. Both
// phases overlap; parity double-buffering makes 1 barrier/step race-free:
// part[(s+1)&1] written at step s is only read at s+1 (after that barrier),
// and its previous readers (step s-1) finished before barrier(s-1).
// wreg is UNION'd (producers 64 v2, consumers 32 v2) so the register
// footprint stays <=128 floats -> no scratch spill (the R1-R6 killer).
__global__ __launch_bounds__(512) void lstm_rec_pipe(
    const uint16_t* __restrict__ h0b, const int* __restrict__ lengths,
    const float* __restrict__ Wih, const float* __restrict__ Whh,
    const float* __restrict__ bih, const float* __restrict__ bhh,
    const float* __restrict__ Wih_b,
    const float* __restrict__ bih_b, const float* __restrict__ bhh_b,
    const float* __restrict__ Wout, const float* __restrict__ bout,
    float* __restrict__ out)
{
    const int b = blockIdx.x;
    const int t = threadIdx.x;
    const int j = t & 63, w = t >> 6;   // w in 0..7
    const int L = lengths[b];
    const bool isProd = (w < 4);

    __shared__ __align__(16) float xch[RCH * 128];   // 16 KB: fp32 h0 rows
    __shared__ __align__(16) float part[2][4][256];  // 8 KB: xW partials
    __shared__ __align__(16) float hrep[4][H];       // consumer h replicas
    __shared__ __align__(16) float ex[2][4][H];      // parity gate exchange
    __shared__ __align__(16) float ybuf[2*H];

    v2 wreg[64];
    float bias = 0.0f;
    if (isProd) {
        #pragma unroll
        for (int q = 0; q < 4; q++) {
            const float4* pw = (const float4*)(Wih + (size_t)(4*j + q) * 128 + 32 * w);
            #pragma unroll
            for (int k = 0; k < 8; k++) {
                float4 v = pw[k];
                wreg[q*16 + 2*k]     = mkv2(v.x, v.y);
                wreg[q*16 + 2*k + 1] = mkv2(v.z, v.w);
            }
        }
    } else {
        const int g = (w - 4) * H + j;
        const float4* pw = (const float4*)(Whh + (size_t)g * H);
        #pragma unroll
        for (int k = 0; k < 16; k++) {
            float4 v = pw[k];
            wreg[2*k]     = mkv2(v.x, v.y);
            wreg[2*k + 1] = mkv2(v.z, v.w);
        }
        bias = bih[g] + bhh[g];
        hrep[w - 4][j] = 0.0f;   // own replica: same-wave ordering, no barrier
    }
    float c = 0.0f, h = 0.0f;

    auto produce = [&](int r, int p) {
        const float4* xr = (const float4*)(xch + r * 128 + 32 * w);
        v2 a0 = mkv2(0,0), a1 = mkv2(0,0), a2 = mkv2(0,0), a3 = mkv2(0,0);
        #pragma unroll
        for (int k = 0; k < 8; k++) {
            float4 xv = xr[k];                    // broadcast b128
            v2 xlo = mkv2(xv.x, xv.y), xhi = mkv2(xv.z, xv.w);
            a0 += wreg[ 0 + 2*k] * xlo; a0 += wreg[ 0 + 2*k + 1] * xhi;
            a1 += wreg[16 + 2*k] * xlo; a1 += wreg[16 + 2*k + 1] * xhi;
            a2 += wreg[32 + 2*k] * xlo; a2 += wreg[32 + 2*k + 1] * xhi;
            a3 += wreg[48 + 2*k] * xlo; a3 += wreg[48 + 2*k + 1] * xhi;
        }
        *(float4*)&part[p][w][4*j] =
            make_float4(a0.x + a0.y, a1.x + a1.y, a2.x + a2.y, a3.x + a3.y);
    };

    for (int s = 0; s < L; s++) {
        const int rr = s & (RCH - 1);
        if (rr == 0) {
            __syncthreads();                      // xch reuse safety
            // stage rows [s, s+RCH) bf16->fp32; lane i writes float2 at 2i:
            // 2 lanes/bank (free), global reads coalesced 4B/lane.
            const uint32_t* src = (const uint32_t*)(h0b + ((size_t)b * TMAX + s) * (2*H));
            for (int i = t; i < RCH * 64; i += 512) {
                uint32_t u = src[i];
                *(float2*)(xch + 2*i) = make_float2(bf2f(u & 0xFFFFu), bf2f(u >> 16));
            }
            __syncthreads();
            if (isProd) produce(0, s & 1);        // boundary row s
            __syncthreads();
        }
        if (isProd) {
            if (s + 1 < L && rr + 1 < RCH)        // lookahead: row s+1
                produce(rr + 1, (s + 1) & 1);
        } else {
            const int g = (w - 4) * H + j;
            const float pa = part[s & 1][0][g] + part[s & 1][1][g]
                           + part[s & 1][2][g] + part[s & 1][3][g];
            v2 a0 = mkv2(pa + bias, 0.0f), a1 = mkv2(0.0f, 0.0f);
            const float4* h4 = (const float4*)hrep[w - 4];
            #pragma unroll
            for (int k = 0; k < 16; k++) {
                float4 hv = h4[k];
                a0 += wreg[2*k]     * mkv2(hv.x, hv.y);
                a1 += wreg[2*k + 1] * mkv2(hv.z, hv.w);
            }
            const float a = (a0.x + a0.y) + (a1.x + a1.y);
            ex[s & 1][w - 4][j] = (w == 6) ? tanhf_(a) : sigmoidf_(a);
        }
        __syncthreads();                          // the per-step barrier
        if (!isProd) {
            const int p = s & 1;
            const float gi = ex[p][0][j], gf = ex[p][1][j];
            const float gg = ex[p][2][j], go = ex[p][3][j];
            c = fmaf(gf, c, gi * gg);
            h = go * tanhf_(c);
            hrep[w - 4][j] = h;
        }
    }

    // ---- epilogue: y = [h1f_last, h1b_first]; logits = y @ Wout^T + bout ---
    if (w == 4) ybuf[j] = h;                      // fwd last h
    __syncthreads();
    const float* xrow = xch + ((L - 1) & (RCH - 1)) * 128;  // h0 row L-1, fp32
    float* gb = &part[0][0][0];
    if (t < 256) {  // bwd first step, zero state -> Whh_l1b unused
        const float4* wb = (const float4*)(Wih_b + (size_t)t * 128);
        const float4* xv = (const float4*)xrow;
        v2 a0 = mkv2(bih_b[t] + bhh_b[t], 0.0f), a1 = mkv2(0.0f, 0.0f);
        #pragma unroll
        for (int k = 0; k < 32; k++) {
            float4 wv = wb[k], xk = xv[k];
            a0 += mkv2(wv.x, wv.y) * mkv2(xk.x, xk.y);
            a1 += mkv2(wv.z, wv.w) * mkv2(xk.z, xk.w);
        }
        const float a = (a0.x + a0.y) + (a1.x + a1.y);
        gb[t] = (t >= 128 && t < 192) ? tanhf_(a) : sigmoidf_(a);
    }
    __syncthreads();
    if (t < 64) {
        const float gi = gb[t], gg = gb[128 + t], go = gb[192 + t];
        ybuf[H + t] = go * tanhf_(gi * gg);       // c_prev = 0, f unused
    }
    __syncthreads();

    const float4* yv = (const float4*)ybuf;
    for (int o = t; o < NC; o += 512) {
        const float4* wr = (const float4*)(Wout + (size_t)o * (2*H));
        v2 a0 = mkv2(bout[o], 0.0f), a1 = mkv2(0.0f, 0.0f);
        #pragma unroll
        for (int k = 0; k < 32; k++) {
            float4 wv = wr[k], yy = yv[k];
            a0 += mkv2(wv.x, wv.y) * mkv2(yy.x, yy.y);
            a1 += mkv2(wv.z, wv.w) * mkv2(yy.z, yy.w);
        }
        out[(size_t)b * NC + o] = (a0.x + a0.y) + (a1.x + a1.y);
    }
}

extern "C" void kernel_launch(void* const* d_in, const int* in_sizes, int n_in,
                              void* d_out, int out_size, void* d_ws, size_t ws_size,
                              hipStream_t stream) {
    const float* x        = (const float*)d_in[0];
    const int*   lengths  = (const int*)  d_in[1];
    const float* Wih_l0f  = (const float*)d_in[2];
    const float* Whh_l0f  = (const float*)d_in[3];
    const float* bih_l0f  = (const float*)d_in[4];
    const float* bhh_l0f  = (const float*)d_in[5];
    const float* Wih_l0b  = (const float*)d_in[6];
    const float* Whh_l0b  = (const float*)d_in[7];
    const float* bih_l0b  = (const float*)d_in[8];
    const float* bhh_l0b  = (const float*)d_in[9];
    const float* Wih_l1f  = (const float*)d_in[10];
    const float* Whh_l1f  = (const float*)d_in[11];
    const float* bih_l1f  = (const float*)d_in[12];
    const float* bhh_l1f  = (const float*)d_in[13];
    const float* Wih_l1b  = (const float*)d_in[14];
    // d_in[15] = Whh_l1b: unused (backward dir only needs its first step, h=0)
    const float* bih_l1b  = (const float*)d_in[16];
    const float* bhh_l1b  = (const float*)d_in[17];
    const float* Wout     = (const float*)d_in[18];
    const float* bout     = (const float*)d_in[19];
    float* out = (float*)d_out;

    // ws: h0 bf16 [B,T,2H] = 128 MiB
    uint16_t* h0b = (uint16_t*)d_ws;

    lstm_layer0_p2<<<dim3(2 * BATCH), 128, 0, stream>>>(
        x, lengths,
        Wih_l0f, Whh_l0f, bih_l0f, bhh_l0f,
        Wih_l0b, Whh_l0b, bih_l0b, bhh_l0b, h0b);

    lstm_rec_pipe<<<dim3(BATCH), 512, 0, stream>>>(
        h0b, lengths,
        Wih_l1f, Whh_l1f, bih_l1f, bhh_l1f,
        Wih_l1b, bih_l1b, bhh_l1b, Wout, bout, out);
}